// Round 1
// baseline (95.526 us; speedup 1.0000x reference)
//
#include <hip/hip_runtime.h>

// DCT per 8x8 block: out[y][v] = sum_x (D@D)[v][x] * in[x][y]  (per block)
// x: [16,64,256,256] f32, W=256 => one (b,c,nh) strip of 8 rows = 2048
// contiguous floats. One 256-thread WG per strip.

#define PP 8
#define STRIP_W 256
#define STRIP_FLOATS (PP * STRIP_W)   // 2048
#define OUT_STRIDE 260                // pad: conflict-free b128 writes

__global__ __launch_bounds__(256)
void dct_strip_kernel(const float* __restrict__ x,
                      const float* __restrict__ D,
                      float* __restrict__ out) {
    __shared__ __align__(16) float s_in[STRIP_FLOATS];            // [8][256]
    __shared__ __align__(16) float s_out[PP * OUT_STRIDE];        // [8][260]
    __shared__ float s_E[64];                                     // E = D@D

    const int t = threadIdx.x;
    const size_t base = (size_t)blockIdx.x * STRIP_FLOATS;

    // E = D @ D (broadcast reads of 256 B of D; hits L1/L2)
    if (t < 64) {
        const int v = t >> 3, xx = t & 7;
        float acc = 0.f;
#pragma unroll
        for (int u = 0; u < 8; ++u) acc += D[v * 8 + u] * D[u * 8 + xx];
        s_E[t] = acc;
    }

    // Coalesced load: strip is contiguous; 2 x float4 per thread.
    const float4* gin = reinterpret_cast<const float4*>(x + base);
    float4* s_in4 = reinterpret_cast<float4*>(s_in);
    s_in4[t]       = gin[t];
    s_in4[t + 256] = gin[t + 256];

    __syncthreads();

    // thread t -> block-col bcol = t>>3 (0..31), output row y = t&7
    const int bcol = t >> 3;
    const int y = t & 7;
    const int colbase = bcol * PP;

    float xc[8];
#pragma unroll
    for (int k = 0; k < 8; ++k)
        xc[k] = s_in[k * STRIP_W + colbase + y];   // bank = t%32 -> 2-way, free

    float o[8];
#pragma unroll
    for (int v = 0; v < 8; ++v) {
        float acc = 0.f;
#pragma unroll
        for (int k = 0; k < 8; ++k) acc += s_E[v * 8 + k] * xc[k];  // E broadcast
        o[v] = acc;
    }

    // two b128 writes; row stride 260 words -> start banks {0,4,..,28} per
    // 8-lane group -> conflict-free
    float4* so0 = reinterpret_cast<float4*>(&s_out[y * OUT_STRIDE + colbase]);
    so0[0] = make_float4(o[0], o[1], o[2], o[3]);
    so0[1] = make_float4(o[4], o[5], o[6], o[7]);

    __syncthreads();

    // Coalesced store: wave w reads row w of s_out linearly (conflict-free).
    float4* gout = reinterpret_cast<float4*>(out + base);
#pragma unroll
    for (int i = 0; i < 2; ++i) {
        const int idx = t + i * 256;          // float4 index in [0,512)
        const int r = (idx * 4) >> 8;         // row 0..7
        const int c = (idx * 4) & 255;        // col
        gout[idx] = *reinterpret_cast<const float4*>(&s_out[r * OUT_STRIDE + c]);
    }
}

extern "C" void kernel_launch(void* const* d_in, const int* in_sizes, int n_in,
                              void* d_out, int out_size, void* d_ws, size_t ws_size,
                              hipStream_t stream) {
    const float* x = (const float*)d_in[0];
    const float* D = (const float*)d_in[1];
    float* out = (float*)d_out;

    const int n_strips = in_sizes[0] / STRIP_FLOATS;   // 16*64*32 = 32768
    dct_strip_kernel<<<n_strips, 256, 0, stream>>>(x, D, out);
}

// Round 3
// 86.715 us; speedup vs baseline: 1.1016x; 1.1016x over previous
//
#include <hip/hip_runtime.h>

// DCT per 8x8 block: out[y][v] = sum_x (D@D)[v][x] * in[x][y]  (per block)
// x: [16,64,256,256] f32, W=256 => one (b,c,nh) strip of 8 rows = 2048
// contiguous floats. One 256-thread WG per strip.
//
// Key identity: thread t owns (bcol = t>>3, y = t&7), and its input column
// index is colbase + y = 8*(t>>3) + (t&7) = t. So the compute-phase input
// read is strip[k*256 + t] -- already perfectly coalesced against GLOBAL
// memory. No input LDS staging needed; only the output needs an LDS
// transpose for coalesced stores.

#define PP 8
#define STRIP_W 256
#define STRIP_FLOATS (PP * STRIP_W)   // 2048
#define OUT_STRIDE 260                // pad for conflict-light b128 writes

typedef float f32x4 __attribute__((ext_vector_type(4)));  // native vec: ok for nontemporal builtins

__global__ __launch_bounds__(256)
void dct_strip_kernel(const float* __restrict__ x,
                      const float* __restrict__ D,
                      float* __restrict__ out) {
    __shared__ __align__(16) float s_out[PP * OUT_STRIDE];   // [8][260]
    __shared__ float s_E[64];                                // E = D@D

    const int t = threadIdx.x;
    const size_t base = (size_t)blockIdx.x * STRIP_FLOATS;

    // E = D @ D (broadcast reads of 256 B of D; cached, NOT nontemporal)
    if (t < 64) {
        const int v = t >> 3, xx = t & 7;
        float acc = 0.f;
#pragma unroll
        for (int u = 0; u < 8; ++u) acc += D[v * 8 + u] * D[u * 8 + xx];
        s_E[t] = acc;
    }

    // Direct coalesced streaming loads: lane t reads column t of the strip.
    float xc[8];
#pragma unroll
    for (int k = 0; k < 8; ++k)
        xc[k] = __builtin_nontemporal_load(&x[base + k * STRIP_W + t]);

    __syncthreads();   // s_E ready

    const int y = t & 7;
    const int colbase = (t >> 3) * PP;

    float o[8];
#pragma unroll
    for (int v = 0; v < 8; ++v) {
        float acc = 0.f;
#pragma unroll
        for (int k = 0; k < 8; ++k) acc += s_E[v * 8 + k] * xc[k];  // E broadcast
        o[v] = acc;
    }

    // Transpose-stage output: row stride 260 words spreads b128 start banks.
    f32x4* so = reinterpret_cast<f32x4*>(&s_out[y * OUT_STRIDE + colbase]);
    so[0] = (f32x4){o[0], o[1], o[2], o[3]};
    so[1] = (f32x4){o[4], o[5], o[6], o[7]};

    __syncthreads();

    // Coalesced nontemporal stores: block reads s_out linearly.
    f32x4* gout = reinterpret_cast<f32x4*>(out + base);
#pragma unroll
    for (int i = 0; i < 2; ++i) {
        const int idx = t + i * 256;          // float4 index in [0,512)
        const int r = (idx * 4) >> 8;         // row 0..7
        const int c = (idx * 4) & 255;        // col
        f32x4 v = *reinterpret_cast<const f32x4*>(&s_out[r * OUT_STRIDE + c]);
        __builtin_nontemporal_store(v, gout + idx);
    }
}

extern "C" void kernel_launch(void* const* d_in, const int* in_sizes, int n_in,
                              void* d_out, int out_size, void* d_ws, size_t ws_size,
                              hipStream_t stream) {
    const float* x = (const float*)d_in[0];
    const float* D = (const float*)d_in[1];
    float* out = (float*)d_out;

    const int n_strips = in_sizes[0] / STRIP_FLOATS;   // 16*64*32 = 32768
    dct_strip_kernel<<<n_strips, 256, 0, stream>>>(x, D, out);
}